// Round 4
// baseline (205.059 us; speedup 1.0000x reference)
//
#include <hip/hip_runtime.h>
#include <stdint.h>

typedef unsigned short u16;
typedef short bf16x8 __attribute__((ext_vector_type(8)));
typedef float f32x4 __attribute__((ext_vector_type(4)));

#define NOB 32
#define ABI 8
#define BSZ 128
#define INF 4096
#define OUTF 4096
#define LRK 64
#define KT2 1280          // padded union K per o-pair: 1152 band + 64 lowrank + 64 zero
#define NST 16            // o-supertiles (pairs)

__device__ __forceinline__ u16 f2bf(float f) {
    uint32_t u = __float_as_uint(f);
    u += 0x7fffu + ((u >> 16) & 1u);
    return (u16)(u >> 16);
}

__device__ __forceinline__ void async16(const u16* g, u16* l) {
    __builtin_amdgcn_global_load_lds(
        (const __attribute__((address_space(1))) uint32_t*)g,
        (__attribute__((address_space(3))) uint32_t*)l, 16, 0, 0);
}

#define FENCE() asm volatile("" ::: "memory")

// ---------------------------------------------------------------------------
// Kernel 1: pack Wb2[os][c2(256)][k(1280)] bf16 + L1b.
// Lanes sweep c2 (c fastest) so W reads are coalesced; 2B writes at stride
// KT2 merge in L2 (per-os region is 640 KB).
// block bid<20480: (os,k) = (bid/1280, bid%1280); thread t = c2.
// ---------------------------------------------------------------------------
__global__ __launch_bounds__(256) void gm_prep(
        const float* __restrict__ W, const float* __restrict__ L1,
        const float* __restrict__ L2,
        u16* __restrict__ Wb2, u16* __restrict__ L1b) {
    int bid = blockIdx.x;
    int t = threadIdx.x;
    if (bid < NST * KT2) {
        int os = bid / KT2;
        int k  = bid % KT2;
        int c  = t & 127, hh = t >> 7;
        int o  = 2 * os + hh;
        int rel = k - (hh << 7);
        float v = 0.f;
        if (k < 1152) {
            if (rel >= 0 && rel < 1024) {
                int j = rel >> 7, b = rel & 127;
                int i = (o + 25 + j) & 31;      // (o-7+j) mod 32
                int a = 7 - j;
                v = W[((i * BSZ + b) * ABI + a) * BSZ + c];
            }
        } else if (k < 1216) {
            v = L2[(o * BSZ + c) * LRK + (k - 1152)];
        }
        Wb2[((size_t)os * 256 + t) * KT2 + k] = f2bf(v);
    } else {
        int i2 = (bid - NST * KT2) * 256 + t;   // 1024 blocks -> 262144 elems
        L1b[i2] = f2bf(L1[i2]);
    }
}

// ---------------------------------------------------------------------------
// Kernel 2: one pass over x (f32): write x_bf16 and h = x @ L1^T (bf16).
// 512 blocks x 512 thr (8 waves). Block = 16 rows; wave w covers K slice
// [w*512, w*512+512). LDS reduce 8 partials.
// ---------------------------------------------------------------------------
__global__ __launch_bounds__(512) void gm_cast_h(
        const float* __restrict__ x, const u16* __restrict__ L1b,
        u16* __restrict__ xb, u16* __restrict__ hb) {
    __shared__ float red[8][4][256];
    int t = threadIdx.x;
    int w = t >> 6, lane = t & 63;
    int lr = lane & 15, lk = (lane >> 4) << 3;
    int rb = blockIdx.x * 16;
    int row = rb + lr;
    f32x4 acc[4];
#pragma unroll
    for (int ni = 0; ni < 4; ++ni) acc[ni] = (f32x4){0.f, 0.f, 0.f, 0.f};
    const int k_base = w * 512;
    for (int ks = 0; ks < 16; ++ks) {
        int k0 = k_base + ks * 32 + lk;
        const float* xp = x + (size_t)row * INF + k0;
        f32x4 x0 = *reinterpret_cast<const f32x4*>(xp);
        f32x4 x1 = *reinterpret_cast<const f32x4*>(xp + 4);
        bf16x8 af;
        af[0] = (short)f2bf(x0[0]); af[1] = (short)f2bf(x0[1]);
        af[2] = (short)f2bf(x0[2]); af[3] = (short)f2bf(x0[3]);
        af[4] = (short)f2bf(x1[0]); af[5] = (short)f2bf(x1[1]);
        af[6] = (short)f2bf(x1[2]); af[7] = (short)f2bf(x1[3]);
        *reinterpret_cast<bf16x8*>(xb + (size_t)row * INF + k0) = af;
#pragma unroll
        for (int ni = 0; ni < 4; ++ni) {
            bf16x8 bv = *reinterpret_cast<const bf16x8*>(
                L1b + (size_t)(ni * 16 + lr) * INF + k0);
            acc[ni] = __builtin_amdgcn_mfma_f32_16x16x32_bf16(af, bv, acc[ni], 0, 0, 0);
        }
    }
#pragma unroll
    for (int ni = 0; ni < 4; ++ni)
#pragma unroll
        for (int j = 0; j < 4; ++j) red[w][ni][lane * 4 + j] = acc[ni][j];
    __syncthreads();
    if (t < 64) {
#pragma unroll
        for (int ni = 0; ni < 4; ++ni)
#pragma unroll
            for (int j = 0; j < 4; ++j) {
                float s = 0.f;
#pragma unroll
                for (int ww = 0; ww < 8; ++ww) s += red[ww][ni][lane * 4 + j];
                int r_ = rb + ((lane >> 4) << 2) + j;
                int c_ = ni * 16 + (lane & 15);
                hb[(size_t)r_ * LRK + c_] = f2bf(s);
            }
    }
}

// ---------------------------------------------------------------------------
// Kernel 3: 256x256 8-phase GEMM with register-cached fragments.
// 8 waves (2Mx4N). Phase order per K-tile: (0,0)->(0,1)->(1,1)->(1,0);
// A frags reused across NH, both B half-sets held in regs -> 24 ds_read_b128
// per wave per K-tile (phase 3 reads nothing). Stage 1 half per phase,
// vmcnt(4), single barrier per phase.
// ---------------------------------------------------------------------------
__global__ __launch_bounds__(512) void gm_gemm(
        const u16* __restrict__ xb, const u16* __restrict__ hb,
        const u16* __restrict__ Wb2, float* __restrict__ out) {
    __shared__ u16 As[2][2][8192];   // [slot][half][128*64]  64 KB
    __shared__ u16 Bs[2][2][8192];   // 64 KB

    int os = blockIdx.x;             // 0..15 fast: L3 set = one mt-stripe
    int mt = blockIdx.y;             // 0..31 slow
    int mbase = mt * 256;
    const u16* wb = Wb2 + (size_t)os * (256 * KT2);
    int cb0 = ((2 * os + 25) * BSZ) & (INF - 1);

    int t = threadIdx.x;
    int lane = t & 63, w = t >> 6;
    int wr = w >> 2, wc = w & 3;     // 2M x 4N
    int lr = lane & 15, g4 = lane >> 4;

    // staging geometry
    int sl = t & 7, row0 = t >> 3;
    int swo = (sl ^ (row0 & 7)) << 3;
    const u16* xa  = xb + (size_t)(mbase + row0) * INF + swo;
    const u16* ha  = hb + (size_t)(mbase + row0) * LRK + swo;
    const u16* wba = wb + (size_t)row0 * KT2 + swo;
    u16* AsD = &As[0][0][0] + t * 8;
    u16* BsD = &Bs[0][0][0] + t * 8;

#define STAGE_A_(Tn, SD, H) do {                                            \
    u16* d_ = AsD + (SD) * 16384 + (H) * 8192;                              \
    if ((Tn) < 18) {                                                        \
        int colT_ = (cb0 + (Tn) * 64) & (INF - 1);                          \
        async16(xa + (size_t)((H) * 128) * INF + colT_, d_);                \
        async16(xa + (size_t)((H) * 128 + 64) * INF + colT_, d_ + 4096);    \
    } else {                                                                \
        async16(ha + (H) * 128 * LRK, d_);                                  \
        async16(ha + ((H) * 128 + 64) * LRK, d_ + 4096);                    \
    }                                                                       \
} while (0)
#define STAGE_B_(Tn, SD, H) do {                                            \
    u16* d_ = BsD + (SD) * 16384 + (H) * 8192;                              \
    async16(wba + (size_t)((H) * 128) * KT2 + (Tn) * 64, d_);               \
    async16(wba + (size_t)((H) * 128 + 64) * KT2 + (Tn) * 64, d_ + 4096);   \
} while (0)

    const u16* Abase = &As[0][0][0];
    const u16* Bbase = &Bs[0][0][0];
    int arow = (wr * 64 + lr) * 64;
    int brow = (wc * 32 + lr) * 64;
    int ksw0 = ((g4) ^ (lr & 7)) << 3;
    int ksw1 = ((4 + g4) ^ (lr & 7)) << 3;

    f32x4 acc[2][2][4][2];
#pragma unroll
    for (int p = 0; p < 2; ++p)
#pragma unroll
        for (int q = 0; q < 2; ++q)
#pragma unroll
            for (int m = 0; m < 4; ++m)
#pragma unroll
                for (int n = 0; n < 2; ++n) acc[p][q][m][n] = (f32x4){0,0,0,0};

    // fragment registers (live across phases)
    bf16x8 a0k0, a1k0, a2k0, a3k0, a0k1, a1k1, a2k1, a3k1;   // A current half
    bf16x8 p0k0, p1k0, p0k1, p1k1;                            // B half 0
    bf16x8 q0k0, q1k0, q0k1, q1k1;                            // B half 1

#define READ_A(S, H) do {                                                    \
    const u16* Ab_ = Abase + (S) * 16384 + (H) * 8192;                       \
    a0k0 = *(const bf16x8*)(Ab_ + arow + 0 * 1024 + ksw0);                   \
    a1k0 = *(const bf16x8*)(Ab_ + arow + 1 * 1024 + ksw0);                   \
    a2k0 = *(const bf16x8*)(Ab_ + arow + 2 * 1024 + ksw0);                   \
    a3k0 = *(const bf16x8*)(Ab_ + arow + 3 * 1024 + ksw0);                   \
    a0k1 = *(const bf16x8*)(Ab_ + arow + 0 * 1024 + ksw1);                   \
    a1k1 = *(const bf16x8*)(Ab_ + arow + 1 * 1024 + ksw1);                   \
    a2k1 = *(const bf16x8*)(Ab_ + arow + 2 * 1024 + ksw1);                   \
    a3k1 = *(const bf16x8*)(Ab_ + arow + 3 * 1024 + ksw1);                   \
} while (0)
#define READ_B0(S) do {                                                      \
    const u16* Bb_ = Bbase + (S) * 16384;                                    \
    p0k0 = *(const bf16x8*)(Bb_ + brow + 0 * 1024 + ksw0);                   \
    p1k0 = *(const bf16x8*)(Bb_ + brow + 1 * 1024 + ksw0);                   \
    p0k1 = *(const bf16x8*)(Bb_ + brow + 0 * 1024 + ksw1);                   \
    p1k1 = *(const bf16x8*)(Bb_ + brow + 1 * 1024 + ksw1);                   \
} while (0)
#define READ_B1(S) do {                                                      \
    const u16* Bb_ = Bbase + (S) * 16384 + 8192;                             \
    q0k0 = *(const bf16x8*)(Bb_ + brow + 0 * 1024 + ksw0);                   \
    q1k0 = *(const bf16x8*)(Bb_ + brow + 1 * 1024 + ksw0);                   \
    q0k1 = *(const bf16x8*)(Bb_ + brow + 0 * 1024 + ksw1);                   \
    q1k1 = *(const bf16x8*)(Bb_ + brow + 1 * 1024 + ksw1);                   \
} while (0)

#define SYNC(VMC)                                                            \
    asm volatile("s_waitcnt vmcnt(" VMC ")" ::: "memory");                   \
    FENCE(); __builtin_amdgcn_s_barrier(); FENCE();                          \
    asm volatile("s_waitcnt lgkmcnt(0)" ::: "memory");                       \
    __builtin_amdgcn_sched_barrier(0);

#define MFMA16Q(MH, NH, B0, B1, B2, B3)                                      \
    __builtin_amdgcn_s_setprio(1);                                           \
    acc[MH][NH][0][0] = __builtin_amdgcn_mfma_f32_16x16x32_bf16(a0k0, B0, acc[MH][NH][0][0], 0,0,0); \
    acc[MH][NH][0][1] = __builtin_amdgcn_mfma_f32_16x16x32_bf16(a0k0, B1, acc[MH][NH][0][1], 0,0,0); \
    acc[MH][NH][1][0] = __builtin_amdgcn_mfma_f32_16x16x32_bf16(a1k0, B0, acc[MH][NH][1][0], 0,0,0); \
    acc[MH][NH][1][1] = __builtin_amdgcn_mfma_f32_16x16x32_bf16(a1k0, B1, acc[MH][NH][1][1], 0,0,0); \
    acc[MH][NH][2][0] = __builtin_amdgcn_mfma_f32_16x16x32_bf16(a2k0, B0, acc[MH][NH][2][0], 0,0,0); \
    acc[MH][NH][2][1] = __builtin_amdgcn_mfma_f32_16x16x32_bf16(a2k0, B1, acc[MH][NH][2][1], 0,0,0); \
    acc[MH][NH][3][0] = __builtin_amdgcn_mfma_f32_16x16x32_bf16(a3k0, B0, acc[MH][NH][3][0], 0,0,0); \
    acc[MH][NH][3][1] = __builtin_amdgcn_mfma_f32_16x16x32_bf16(a3k0, B1, acc[MH][NH][3][1], 0,0,0); \
    acc[MH][NH][0][0] = __builtin_amdgcn_mfma_f32_16x16x32_bf16(a0k1, B2, acc[MH][NH][0][0], 0,0,0); \
    acc[MH][NH][0][1] = __builtin_amdgcn_mfma_f32_16x16x32_bf16(a0k1, B3, acc[MH][NH][0][1], 0,0,0); \
    acc[MH][NH][1][0] = __builtin_amdgcn_mfma_f32_16x16x32_bf16(a1k1, B2, acc[MH][NH][1][0], 0,0,0); \
    acc[MH][NH][1][1] = __builtin_amdgcn_mfma_f32_16x16x32_bf16(a1k1, B3, acc[MH][NH][1][1], 0,0,0); \
    acc[MH][NH][2][0] = __builtin_amdgcn_mfma_f32_16x16x32_bf16(a2k1, B2, acc[MH][NH][2][0], 0,0,0); \
    acc[MH][NH][2][1] = __builtin_amdgcn_mfma_f32_16x16x32_bf16(a2k1, B3, acc[MH][NH][2][1], 0,0,0); \
    acc[MH][NH][3][0] = __builtin_amdgcn_mfma_f32_16x16x32_bf16(a3k1, B2, acc[MH][NH][3][0], 0,0,0); \
    acc[MH][NH][3][1] = __builtin_amdgcn_mfma_f32_16x16x32_bf16(a3k1, B3, acc[MH][NH][3][1], 0,0,0); \
    __builtin_amdgcn_s_setprio(0);

// Main group: compute tile in slot S, stage tile TN into slot NS.
#define GROUP_MAIN(S, NS, TN) do {                                           \
    READ_A(S, 0); READ_B0(S);                                                \
    STAGE_B_(TN, NS, 0);                                                     \
    SYNC("4")                                                                \
    MFMA16Q(0, 0, p0k0, p1k0, p0k1, p1k1)                                    \
    READ_B1(S);                                                              \
    STAGE_A_(TN, NS, 0);                                                     \
    SYNC("4")                                                                \
    MFMA16Q(0, 1, q0k0, q1k0, q0k1, q1k1)                                    \
    READ_A(S, 1);                                                            \
    STAGE_B_(TN, NS, 1);                                                     \
    SYNC("4")                                                                \
    MFMA16Q(1, 1, q0k0, q1k0, q0k1, q1k1)                                    \
    STAGE_A_(TN, NS, 1);                                                     \
    SYNC("4")                                                                \
    MFMA16Q(1, 0, p0k0, p1k0, p0k1, p1k1)                                    \
} while (0)

#define GROUP_TAIL(S) do {                                                   \
    READ_A(S, 0); READ_B0(S);                                                \
    SYNC("2")                                                                \
    MFMA16Q(0, 0, p0k0, p1k0, p0k1, p1k1)                                    \
    READ_B1(S);                                                              \
    SYNC("0")                                                                \
    MFMA16Q(0, 1, q0k0, q1k0, q0k1, q1k1)                                    \
    READ_A(S, 1);                                                            \
    SYNC("0")                                                                \
    MFMA16Q(1, 1, q0k0, q1k0, q0k1, q1k1)                                    \
    SYNC("0")                                                                \
    MFMA16Q(1, 0, p0k0, p1k0, p0k1, p1k1)                                    \
} while (0)

    // prologue: stage tile 0 into slot 0 (order B0,A0,B1,A1)
    STAGE_B_(0, 0, 0); STAGE_A_(0, 0, 0); STAGE_B_(0, 0, 1); STAGE_A_(0, 0, 1);
    asm volatile("s_waitcnt vmcnt(4)" ::: "memory");
    FENCE(); __builtin_amdgcn_s_barrier(); FENCE();

#pragma unroll 1
    for (int T = 0; T < 18; T += 2) {
        GROUP_MAIN(0, 1, T + 1);
        GROUP_MAIN(1, 0, T + 2);
    }
    GROUP_MAIN(0, 1, 19);   // tile 18, stage tile 19
    GROUP_TAIL(1);          // tile 19

    // epilogue: C/D col=lane&15, row=(lane>>4)*4+j
    int orow = mbase + wr * 64 + (g4 << 2);
    int ocol = os * 256 + wc * 32 + lr;
#pragma unroll
    for (int mh = 0; mh < 2; ++mh)
#pragma unroll
        for (int nh = 0; nh < 2; ++nh)
#pragma unroll
            for (int m = 0; m < 4; ++m)
#pragma unroll
                for (int n = 0; n < 2; ++n) {
                    float* p_ = out + (size_t)(orow + mh * 128 + m * 16) * OUTF
                              + ocol + nh * 128 + n * 16;
#pragma unroll
                    for (int j = 0; j < 4; ++j)
                        p_[(size_t)j * OUTF] = acc[mh][nh][m][n][j];
                }
}

extern "C" void kernel_launch(void* const* d_in, const int* in_sizes, int n_in,
                              void* d_out, int out_size, void* d_ws, size_t ws_size,
                              hipStream_t stream) {
    const float* x  = (const float*)d_in[0];   // [8192][4096]
    const float* W  = (const float*)d_in[1];   // [4096][8][128]
    const float* L1 = (const float*)d_in[2];   // [64][4096]
    const float* L2 = (const float*)d_in[3];   // [4096][64]
    float* out = (float*)d_out;

    char* ws = (char*)d_ws;
    u16* xb  = (u16*)(ws);                       // 67108864 B
    u16* hb  = (u16*)(ws + 67108864);            // 1048576 B
    u16* Wb2 = (u16*)(ws + 68157440);            // 13107200 B
    u16* L1b = (u16*)(ws + 81264640);            // 524288 B

    gm_prep<<<dim3(NST * KT2 + 1024), dim3(256), 0, stream>>>(W, L1, L2, Wb2, L1b);
    gm_cast_h<<<dim3(512), dim3(512), 0, stream>>>(x, L1b, xb, hb);
    gm_gemm<<<dim3(16, 32), dim3(512), 0, stream>>>(xb, hb, Wb2, out);
}

// Round 5
// 175.423 us; speedup vs baseline: 1.1689x; 1.1689x over previous
//
#include <hip/hip_runtime.h>
#include <stdint.h>

typedef unsigned short u16;
typedef short bf16x8 __attribute__((ext_vector_type(8)));
typedef float f32x4 __attribute__((ext_vector_type(4)));
typedef unsigned short u16x4 __attribute__((ext_vector_type(4)));

#define NOB 32
#define ABI 8
#define BSZ 128
#define INF 4096
#define OUTF 4096
#define LRK 64
#define KT2 1280          // Wb2 row stride; gemm reads only [0,1216)
#define NST 16            // o-supertiles (pairs)
#define NKT 19            // 18 band K-tiles + 1 lowrank tile (64 each = 1216)

__device__ __forceinline__ u16 f2bf(float f) {
    uint32_t u = __float_as_uint(f);
    u += 0x7fffu + ((u >> 16) & 1u);
    return (u16)(u >> 16);
}

__device__ __forceinline__ void async16(const u16* g, u16* l) {
    __builtin_amdgcn_global_load_lds(
        (const __attribute__((address_space(1))) uint32_t*)g,
        (__attribute__((address_space(3))) uint32_t*)l, 16, 0, 0);
}

#define FENCE() asm volatile("" ::: "memory")

// ---------------------------------------------------------------------------
// Kernel 1: pack Wb2[os][c2(256)][k] bf16 (k-contiguous rows) + L1b.
// bid 0..255   : W 128x128 tile transpose via swizzled LDS. bid=(o<<3)|j.
//                src W[(i*128+b)*8+a)*128+c] rows coalesced; dst rows
//                k=hh*128+j*128+b contiguous per c2-row.
// bid 256..287 : L2 copy (no transpose needed) into k [1152,1216).
// bid 288..319 : zero-fill band pad (hh0: k[1024,1152), hh1: k[0,128)).
// bid 320..575 : L1b f32->bf16 vectorized copy.
// ---------------------------------------------------------------------------
__global__ __launch_bounds__(256) void gm_prep(
        const float* __restrict__ W, const float* __restrict__ L1,
        const float* __restrict__ L2,
        u16* __restrict__ Wb2, u16* __restrict__ L1b) {
    __shared__ u16 tile[128 * 128];
    int bid = blockIdx.x;
    int t = threadIdx.x;
    if (bid < 256) {
        int j = bid & 7, o = bid >> 3;
        int os = o >> 1, hh = o & 1;
        int i = (o + 25 + j) & 31;             // (o-7+j) mod 32
        int a = 7 - j;
        // read: 2 b-rows per pass, c coalesced
        int c = t & 127, b0 = t >> 7;
        const float* src = W + ((size_t)(i * BSZ) * ABI + a) * BSZ + c;
#pragma unroll 4
        for (int p = 0; p < 64; ++p) {
            int b = p * 2 + b0;
            float v = src[(size_t)b * (ABI * BSZ)];
            tile[b * 128 + (c ^ ((b & 31) << 1))] = f2bf(v);
        }
        __syncthreads();
        // write: 2 c-rows per pass, b (=k) coalesced
        int b = t & 127, c0 = t >> 7;
        u16* dst = Wb2 + ((size_t)os * 256 + hh * 128) * KT2
                 + (size_t)(hh * 128 + j * 128 + b);
#pragma unroll 4
        for (int p = 0; p < 64; ++p) {
            int cc = p * 2 + c0;
            dst[(size_t)cc * KT2] = tile[b * 128 + (cc ^ ((b & 31) << 1))];
        }
    } else if (bid < 288) {
        int o = bid - 256;
        int os = o >> 1, hh = o & 1;
        int r = t & 63, c0 = t >> 6;
        for (int p = 0; p < 32; ++p) {
            int c = p * 4 + c0;
            float v = L2[((size_t)o * BSZ + c) * LRK + r];
            Wb2[((size_t)os * 256 + hh * 128 + c) * KT2 + 1152 + r] = f2bf(v);
        }
    } else if (bid < 320) {
        int o = bid - 288;
        int os = o >> 1, hh = o & 1;
        int c = t >> 1;
        int k0 = hh ? 0 : 1024;
        u16* dst = Wb2 + ((size_t)os * 256 + hh * 128 + c) * KT2 + k0 + (t & 1) * 64;
        for (int q = 0; q < 64; ++q) dst[q] = 0;
    } else {
        int idx = ((bid - 320) * 256 + t) * 4;  // < 262144
        f32x4 v = *reinterpret_cast<const f32x4*>(L1 + idx);
        u16x4 o4;
        o4[0] = f2bf(v[0]); o4[1] = f2bf(v[1]); o4[2] = f2bf(v[2]); o4[3] = f2bf(v[3]);
        *reinterpret_cast<u16x4*>(L1b + idx) = o4;
    }
}

// ---------------------------------------------------------------------------
// Kernel 2: one pass over x (f32): write x_bf16 and h = x @ L1^T (bf16).
// 512 blocks x 512 thr (8 waves); block = 16 rows; wave w = K slice of 512.
// ---------------------------------------------------------------------------
__global__ __launch_bounds__(512) void gm_cast_h(
        const float* __restrict__ x, const u16* __restrict__ L1b,
        u16* __restrict__ xb, u16* __restrict__ hb) {
    __shared__ float red[8][4][256];
    int t = threadIdx.x;
    int w = t >> 6, lane = t & 63;
    int lr = lane & 15, lk = (lane >> 4) << 3;
    int rb = blockIdx.x * 16;
    int row = rb + lr;
    f32x4 acc[4];
#pragma unroll
    for (int ni = 0; ni < 4; ++ni) acc[ni] = (f32x4){0.f, 0.f, 0.f, 0.f};
    const int k_base = w * 512;
    for (int ks = 0; ks < 16; ++ks) {
        int k0 = k_base + ks * 32 + lk;
        const float* xp = x + (size_t)row * INF + k0;
        f32x4 x0 = *reinterpret_cast<const f32x4*>(xp);
        f32x4 x1 = *reinterpret_cast<const f32x4*>(xp + 4);
        bf16x8 af;
        af[0] = (short)f2bf(x0[0]); af[1] = (short)f2bf(x0[1]);
        af[2] = (short)f2bf(x0[2]); af[3] = (short)f2bf(x0[3]);
        af[4] = (short)f2bf(x1[0]); af[5] = (short)f2bf(x1[1]);
        af[6] = (short)f2bf(x1[2]); af[7] = (short)f2bf(x1[3]);
        *reinterpret_cast<bf16x8*>(xb + (size_t)row * INF + k0) = af;
#pragma unroll
        for (int ni = 0; ni < 4; ++ni) {
            bf16x8 bv = *reinterpret_cast<const bf16x8*>(
                L1b + (size_t)(ni * 16 + lr) * INF + k0);
            acc[ni] = __builtin_amdgcn_mfma_f32_16x16x32_bf16(af, bv, acc[ni], 0, 0, 0);
        }
    }
#pragma unroll
    for (int ni = 0; ni < 4; ++ni)
#pragma unroll
        for (int j = 0; j < 4; ++j) red[w][ni][lane * 4 + j] = acc[ni][j];
    __syncthreads();
    if (t < 64) {
#pragma unroll
        for (int ni = 0; ni < 4; ++ni)
#pragma unroll
            for (int j = 0; j < 4; ++j) {
                float s = 0.f;
#pragma unroll
                for (int ww = 0; ww < 8; ++ww) s += red[ww][ni][lane * 4 + j];
                int r_ = rb + ((lane >> 4) << 2) + j;
                int c_ = ni * 16 + (lane & 15);
                hb[(size_t)r_ * LRK + c_] = f2bf(s);
            }
    }
}

// ---------------------------------------------------------------------------
// Kernel 3: 256x256 GEMM, ONE barrier per K-tile. 8 waves (2Mx4N), wave out
// 128x64. Per tile: vmcnt(0)+barrier -> 16 ds_read (A0,B0,B1) + 8 stage ->
// 32 MFMA -> 8 ds_read (A1) -> 32 MFMA. No manual lgkmcnt: compiler emits
// counted waits; waves de-sync within the tile so ds_read overlaps MFMA
// across waves. Double-buffered swizzled LDS (staged via pre-swizzled src).
// ---------------------------------------------------------------------------
__global__ __launch_bounds__(512, 2) void gm_gemm(
        const u16* __restrict__ xb, const u16* __restrict__ hb,
        const u16* __restrict__ Wb2, float* __restrict__ out) {
    __shared__ u16 As[2][2][8192];   // [slot][half][128*64]  64 KB
    __shared__ u16 Bs[2][2][8192];   // 64 KB

    int os = blockIdx.x;             // fast
    int mt = blockIdx.y;             // slow
    int mbase = mt * 256;
    const u16* wb = Wb2 + (size_t)os * (256 * KT2);
    int cb0 = ((2 * os + 25) * BSZ) & (INF - 1);

    int t = threadIdx.x;
    int lane = t & 63, w = t >> 6;
    int wr = w >> 2, wc = w & 3;     // 2M x 4N
    int lr = lane & 15, g4 = lane >> 4;

    // staging geometry
    int sl = t & 7, row0 = t >> 3;
    int swo = (sl ^ (row0 & 7)) << 3;
    const u16* xa  = xb + (size_t)(mbase + row0) * INF + swo;
    const u16* ha  = hb + (size_t)(mbase + row0) * LRK + swo;
    const u16* wba = wb + (size_t)row0 * KT2 + swo;
    u16* AsD = &As[0][0][0] + t * 8;
    u16* BsD = &Bs[0][0][0] + t * 8;

#define STAGE_A_(Tn, SD, H) do {                                            \
    u16* d_ = AsD + (SD) * 16384 + (H) * 8192;                              \
    if ((Tn) < 18) {                                                        \
        int colT_ = (cb0 + (Tn) * 64) & (INF - 1);                          \
        async16(xa + (size_t)((H) * 128) * INF + colT_, d_);                \
        async16(xa + (size_t)((H) * 128 + 64) * INF + colT_, d_ + 4096);    \
    } else {                                                                \
        async16(ha + (H) * 128 * LRK, d_);                                  \
        async16(ha + ((H) * 128 + 64) * LRK, d_ + 4096);                    \
    }                                                                       \
} while (0)
#define STAGE_B_(Tn, SD, H) do {                                            \
    u16* d_ = BsD + (SD) * 16384 + (H) * 8192;                              \
    async16(wba + (size_t)((H) * 128) * KT2 + (Tn) * 64, d_);               \
    async16(wba + (size_t)((H) * 128 + 64) * KT2 + (Tn) * 64, d_ + 4096);   \
} while (0)

    const u16* Abase = &As[0][0][0];
    const u16* Bbase = &Bs[0][0][0];
    int arow = (wr * 64 + lr) * 64;
    int brow = (wc * 32 + lr) * 64;
    int ksw0 = ((g4) ^ (lr & 7)) << 3;
    int ksw1 = ((4 + g4) ^ (lr & 7)) << 3;

    f32x4 acc[2][2][4][2];
#pragma unroll
    for (int p = 0; p < 2; ++p)
#pragma unroll
        for (int q = 0; q < 2; ++q)
#pragma unroll
            for (int m = 0; m < 4; ++m)
#pragma unroll
                for (int n = 0; n < 2; ++n) acc[p][q][m][n] = (f32x4){0,0,0,0};

    bf16x8 a0k0, a1k0, a2k0, a3k0, a0k1, a1k1, a2k1, a3k1;   // A current half
    bf16x8 p0k0, p1k0, p0k1, p1k1;                            // B half 0
    bf16x8 q0k0, q1k0, q0k1, q1k1;                            // B half 1

#define READ_A(S, H) do {                                                    \
    const u16* Ab_ = Abase + (S) * 16384 + (H) * 8192;                       \
    a0k0 = *(const bf16x8*)(Ab_ + arow + 0 * 1024 + ksw0);                   \
    a1k0 = *(const bf16x8*)(Ab_ + arow + 1 * 1024 + ksw0);                   \
    a2k0 = *(const bf16x8*)(Ab_ + arow + 2 * 1024 + ksw0);                   \
    a3k0 = *(const bf16x8*)(Ab_ + arow + 3 * 1024 + ksw0);                   \
    a0k1 = *(const bf16x8*)(Ab_ + arow + 0 * 1024 + ksw1);                   \
    a1k1 = *(const bf16x8*)(Ab_ + arow + 1 * 1024 + ksw1);                   \
    a2k1 = *(const bf16x8*)(Ab_ + arow + 2 * 1024 + ksw1);                   \
    a3k1 = *(const bf16x8*)(Ab_ + arow + 3 * 1024 + ksw1);                   \
} while (0)
#define READ_B0(S) do {                                                      \
    const u16* Bb_ = Bbase + (S) * 16384;                                    \
    p0k0 = *(const bf16x8*)(Bb_ + brow + 0 * 1024 + ksw0);                   \
    p1k0 = *(const bf16x8*)(Bb_ + brow + 1 * 1024 + ksw0);                   \
    p0k1 = *(const bf16x8*)(Bb_ + brow + 0 * 1024 + ksw1);                   \
    p1k1 = *(const bf16x8*)(Bb_ + brow + 1 * 1024 + ksw1);                   \
} while (0)
#define READ_B1(S) do {                                                      \
    const u16* Bb_ = Bbase + (S) * 16384 + 8192;                             \
    q0k0 = *(const bf16x8*)(Bb_ + brow + 0 * 1024 + ksw0);                   \
    q1k0 = *(const bf16x8*)(Bb_ + brow + 1 * 1024 + ksw0);                   \
    q0k1 = *(const bf16x8*)(Bb_ + brow + 0 * 1024 + ksw1);                   \
    q1k1 = *(const bf16x8*)(Bb_ + brow + 1 * 1024 + ksw1);                   \
} while (0)

#define MFMA16Q(MH, NH, B0, B1, B2, B3)                                      \
    __builtin_amdgcn_s_setprio(1);                                           \
    acc[MH][NH][0][0] = __builtin_amdgcn_mfma_f32_16x16x32_bf16(a0k0, B0, acc[MH][NH][0][0], 0,0,0); \
    acc[MH][NH][0][1] = __builtin_amdgcn_mfma_f32_16x16x32_bf16(a0k0, B1, acc[MH][NH][0][1], 0,0,0); \
    acc[MH][NH][1][0] = __builtin_amdgcn_mfma_f32_16x16x32_bf16(a1k0, B0, acc[MH][NH][1][0], 0,0,0); \
    acc[MH][NH][1][1] = __builtin_amdgcn_mfma_f32_16x16x32_bf16(a1k0, B1, acc[MH][NH][1][1], 0,0,0); \
    acc[MH][NH][2][0] = __builtin_amdgcn_mfma_f32_16x16x32_bf16(a2k0, B0, acc[MH][NH][2][0], 0,0,0); \
    acc[MH][NH][2][1] = __builtin_amdgcn_mfma_f32_16x16x32_bf16(a2k0, B1, acc[MH][NH][2][1], 0,0,0); \
    acc[MH][NH][3][0] = __builtin_amdgcn_mfma_f32_16x16x32_bf16(a3k0, B0, acc[MH][NH][3][0], 0,0,0); \
    acc[MH][NH][3][1] = __builtin_amdgcn_mfma_f32_16x16x32_bf16(a3k0, B1, acc[MH][NH][3][1], 0,0,0); \
    acc[MH][NH][0][0] = __builtin_amdgcn_mfma_f32_16x16x32_bf16(a0k1, B2, acc[MH][NH][0][0], 0,0,0); \
    acc[MH][NH][0][1] = __builtin_amdgcn_mfma_f32_16x16x32_bf16(a0k1, B3, acc[MH][NH][0][1], 0,0,0); \
    acc[MH][NH][1][0] = __builtin_amdgcn_mfma_f32_16x16x32_bf16(a1k1, B2, acc[MH][NH][1][0], 0,0,0); \
    acc[MH][NH][1][1] = __builtin_amdgcn_mfma_f32_16x16x32_bf16(a1k1, B3, acc[MH][NH][1][1], 0,0,0); \
    acc[MH][NH][2][0] = __builtin_amdgcn_mfma_f32_16x16x32_bf16(a2k1, B2, acc[MH][NH][2][0], 0,0,0); \
    acc[MH][NH][2][1] = __builtin_amdgcn_mfma_f32_16x16x32_bf16(a2k1, B3, acc[MH][NH][2][1], 0,0,0); \
    acc[MH][NH][3][0] = __builtin_amdgcn_mfma_f32_16x16x32_bf16(a3k1, B2, acc[MH][NH][3][0], 0,0,0); \
    acc[MH][NH][3][1] = __builtin_amdgcn_mfma_f32_16x16x32_bf16(a3k1, B3, acc[MH][NH][3][1], 0,0,0); \
    __builtin_amdgcn_s_setprio(0);

// One K-tile: single barrier; reads+stage up front; compiler-counted lgkmcnt.
#define ITER(S, TNEXT, DOSTAGE) do {                                         \
    asm volatile("s_waitcnt vmcnt(0)" ::: "memory");                         \
    FENCE(); __builtin_amdgcn_s_barrier(); FENCE();                          \
    READ_A(S, 0); READ_B0(S); READ_B1(S);                                    \
    if (DOSTAGE) {                                                           \
        STAGE_B_((TNEXT), (S) ^ 1, 0); STAGE_A_((TNEXT), (S) ^ 1, 0);        \
        STAGE_B_((TNEXT), (S) ^ 1, 1); STAGE_A_((TNEXT), (S) ^ 1, 1);        \
    }                                                                        \
    MFMA16Q(0, 0, p0k0, p1k0, p0k1, p1k1)                                    \
    MFMA16Q(0, 1, q0k0, q1k0, q0k1, q1k1)                                    \
    READ_A(S, 1);                                                            \
    MFMA16Q(1, 1, q0k0, q1k0, q0k1, q1k1)                                    \
    MFMA16Q(1, 0, p0k0, p1k0, p0k1, p1k1)                                    \
} while (0)

    // prologue: stage tile 0 into slot 0
    STAGE_B_(0, 0, 0); STAGE_A_(0, 0, 0); STAGE_B_(0, 0, 1); STAGE_A_(0, 0, 1);

#pragma unroll 1
    for (int T = 0; T < 18; T += 2) {
        ITER(0, T + 1, true);
        ITER(1, T + 2, true);     // T=16 stages tile 18 (lowrank)
    }
    ITER(0, 0, false);            // tile 18

    // epilogue: C/D col=lane&15, row=(lane>>4)*4+j
    int orow = mbase + wr * 64 + (g4 << 2);
    int ocol = os * 256 + wc * 32 + lr;
#pragma unroll
    for (int mh = 0; mh < 2; ++mh)
#pragma unroll
        for (int nh = 0; nh < 2; ++nh)
#pragma unroll
            for (int m = 0; m < 4; ++m)
#pragma unroll
                for (int n = 0; n < 2; ++n) {
                    float* p_ = out + (size_t)(orow + mh * 128 + m * 16) * OUTF
                              + ocol + nh * 128 + n * 16;
#pragma unroll
                    for (int j = 0; j < 4; ++j)
                        p_[(size_t)j * OUTF] = acc[mh][nh][m][n][j];
                }
}

extern "C" void kernel_launch(void* const* d_in, const int* in_sizes, int n_in,
                              void* d_out, int out_size, void* d_ws, size_t ws_size,
                              hipStream_t stream) {
    const float* x  = (const float*)d_in[0];   // [8192][4096]
    const float* W  = (const float*)d_in[1];   // [4096][8][128]
    const float* L1 = (const float*)d_in[2];   // [64][4096]
    const float* L2 = (const float*)d_in[3];   // [4096][64]
    float* out = (float*)d_out;

    char* ws = (char*)d_ws;
    u16* xb  = (u16*)(ws);                       // 67108864 B
    u16* hb  = (u16*)(ws + 67108864);            // 1048576 B
    u16* Wb2 = (u16*)(ws + 68157440);            // 13107200 B
    u16* L1b = (u16*)(ws + 81264640);            // 524288 B

    gm_prep<<<dim3(576), dim3(256), 0, stream>>>(W, L1, L2, Wb2, L1b);
    gm_cast_h<<<dim3(512), dim3(512), 0, stream>>>(x, L1b, xb, hb);
    gm_gemm<<<dim3(16, 32), dim3(512), 0, stream>>>(xb, hb, Wb2, out);
}